// Round 7
// baseline (336.693 us; speedup 1.0000x reference)
//
#include <hip/hip_runtime.h>

#define NNODE 50000
#define NEDGE 600000
#define KDIN  239
#define DDIM  128
#define NTILES ((NNODE+15)/16)

typedef __attribute__((ext_vector_type(8))) short short8;
typedef __attribute__((ext_vector_type(4))) float f32x4;

__device__ __forceinline__ float bf2f(ushort u){
  union { unsigned int i; float f; } v; v.i = ((unsigned int)u) << 16; return v.f;
}
__device__ __forceinline__ ushort f2bf(float f){
  union { float f; unsigned int i; } v; v.f = f;
  unsigned int x = v.i;
  unsigned int r = x + 0x7fffu + ((x >> 16) & 1u);
  return (ushort)(r >> 16);
}
// monotone float<->uint encoding for atomicMax on signed floats (>0 for all reals)
__device__ __forceinline__ unsigned fenc(float f){
  union { float f; unsigned u; } v; v.f = f;
  return (v.u & 0x80000000u) ? ~v.u : (v.u | 0x80000000u);
}
__device__ __forceinline__ float fdec(unsigned k){
  union { unsigned u; float f; } v;
  v.u = (k & 0x80000000u) ? (k & 0x7FFFFFFFu) : ~k;
  return v.f;
}

// ---- pre-split weights to transposed bf16 hi/lo [n][Kpad] ----
__global__ __launch_bounds__(256) void splitw_k(
    const float* __restrict__ W_in, const float* __restrict__ W_gat, const float* __restrict__ W_h,
    ushort* __restrict__ BhA, ushort* __restrict__ BlA,
    ushort* __restrict__ BhB, ushort* __restrict__ BlB,
    ushort* __restrict__ BhC, ushort* __restrict__ BlC)
{
  int idx = blockIdx.x*256 + threadIdx.x;
  float v; ushort* ph; ushort* pl; int o;
  if (idx < 128*256){                         // W_in [239,128] -> [n=128][Kpad=256]
    int n = idx >> 8, k = idx & 255;
    v = (k < KDIN) ? W_in[(size_t)k*DDIM + n] : 0.f;
    ph = BhA; pl = BlA; o = idx;
  } else if (idx < 32768 + 16384){            // W_gat [128,128] -> [n][128]
    int j = idx - 32768; int n = j >> 7, k = j & 127;
    v = W_gat[(size_t)k*DDIM + n];
    ph = BhB; pl = BlB; o = j;
  } else {                                    // W_h [128,128] -> [n][128]
    int j = idx - 49152; int n = j >> 7, k = j & 127;
    v = W_h[(size_t)k*DDIM + n];
    ph = BhC; pl = BlC; o = j;
  }
  ushort hi = f2bf(v);
  ph[o] = hi; pl[o] = f2bf(v - bf2f(hi));
}

// ---- pre-split x [N,239] fp32 -> bf16 hi/lo [N,256] (zero-padded K) ----
__global__ __launch_bounds__(256) void splitx_k(const float* __restrict__ x,
    ushort* __restrict__ xh, ushort* __restrict__ xl)
{
  int idx = blockIdx.x*256 + threadIdx.x;      // N*32 threads, 8 elems each
  if (idx >= NNODE*32) return;
  int r = idx >> 5, c0 = (idx & 31) << 3;
  union { uint4 v; ushort u[8]; } oh, ol;
  #pragma unroll
  for (int i=0;i<8;i++){
    int c = c0+i;
    float v = (c < KDIN) ? x[(size_t)r*KDIN + c] : 0.f;
    ushort hi = f2bf(v);
    oh.u[i] = hi; ol.u[i] = f2bf(v - bf2f(hi));
  }
  *(uint4*)(xh + (size_t)r*256 + c0) = oh.v;
  *(uint4*)(xl + (size_t)r*256 + c0) = ol.v;
}

// ---- MFMA GEMM, B fully resident in VGPRs, grid-stride row tiles ----
// EPI 0: leaky(.01)(v+bias) -> bf16 hi/lo
// EPI 1: v -> fp32 g; fused row dots os=g.vs, od=g.vd + global max of dots -> gm[0..1]
// EPI 2: h2=leaky(.01)(v+bias); fused y = h2@W_out + b_out -> outf
template<int KSTEPS, int NT, int EPI>
__global__ __launch_bounds__(256, 1) void gemm3_k(
    const ushort* __restrict__ Ah, const ushort* __restrict__ Al,
    const ushort* __restrict__ Bth, const ushort* __restrict__ Btl,
    const float* __restrict__ bias,
    float* __restrict__ outf, ushort* __restrict__ outh, ushort* __restrict__ outl,
    const float* __restrict__ vs, const float* __restrict__ vd,
    float* __restrict__ os, float* __restrict__ od, unsigned* __restrict__ gm)
{
  constexpr int Kpad = KSTEPS*32;
  constexpr int CS  = 128/(NT*16);             // 1 (gemmB/C) or 2 (gemmA)
  constexpr int NRS = 4/CS;                    // row slots per block
  const int lane = threadIdx.x & 63;
  const int wave = threadIdx.x >> 6;
  const int q = lane >> 4, c = lane & 15;
  const int colBase = (wave & (CS-1)) * (NT*16);
  const int rowSlot = wave >> (CS-1);
  // B preload: wave's entire col-slice x full K, in registers
  short8 bh[KSTEPS][NT], bl[KSTEPS][NT];
  #pragma unroll
  for (int t=0;t<NT;t++){
    const size_t bo = (size_t)(colBase + 16*t + c)*Kpad + q*8;
    #pragma unroll
    for (int s=0;s<KSTEPS;s++){
      bh[s][t] = *(const short8*)(Bth + bo + s*32);
      bl[s][t] = *(const short8*)(Btl + bo + s*32);
    }
  }
  float lmax_s = -3.0e38f, lmax_d = -3.0e38f;
  const int tileStride = gridDim.x * NRS;
  for (int rt = blockIdx.x*NRS + rowSlot; rt < NTILES; rt += tileStride){
    const int rowBase = rt*16;
    const int arow = min(rowBase + c, NNODE-1);
    short8 ah[KSTEPS], al[KSTEPS];
    const ushort* __restrict__ aph = Ah + (size_t)arow*Kpad + q*8;
    const ushort* __restrict__ apl = Al + (size_t)arow*Kpad + q*8;
    #pragma unroll
    for (int s=0;s<KSTEPS;s++){
      ah[s] = *(const short8*)(aph + s*32);
      al[s] = *(const short8*)(apl + s*32);
    }
    f32x4 acc[NT];
    #pragma unroll
    for (int t=0;t<NT;t++) acc[t] = (f32x4){0.f,0.f,0.f,0.f};
    #pragma unroll
    for (int s=0;s<KSTEPS;s++){
      #pragma unroll
      for (int t=0;t<NT;t++){
        acc[t] = __builtin_amdgcn_mfma_f32_16x16x32_bf16(ah[s], bh[s][t], acc[t], 0,0,0);
        acc[t] = __builtin_amdgcn_mfma_f32_16x16x32_bf16(ah[s], bl[s][t], acc[t], 0,0,0);
        acc[t] = __builtin_amdgcn_mfma_f32_16x16x32_bf16(al[s], bh[s][t], acc[t], 0,0,0);
      }
    }
    // epilogue: C/D layout col=lane&15, row=(lane>>4)*4+reg  [m89/m91-verified]
    float pr0[4] = {0,0,0,0}, pr1[4] = {0,0,0,0};
    #pragma unroll
    for (int t=0;t<NT;t++){
      const int col = colBase + 16*t + c;
      const float bv = (EPI != 1) ? bias[col] : 0.f;
      float va=0.f, vb=0.f;
      if (EPI == 1){ va = vs[col]; vb = vd[col]; }
      if (EPI == 2){ va = vs[2*col]; vb = vs[2*col+1]; }
      #pragma unroll
      for (int r=0;r<4;r++){
        const int row = rowBase + q*4 + r;
        float v = acc[t][r] + bv;
        if (EPI != 1) v = (v >= 0.f) ? v : 0.01f*v;
        if (EPI == 0){
          if (row < NNODE){
            const ushort hi = f2bf(v);
            outh[(size_t)row*DDIM + col] = hi;
            outl[(size_t)row*DDIM + col] = f2bf(v - bf2f(hi));
          }
        } else if (EPI == 1){
          if (row < NNODE) outf[(size_t)row*DDIM + col] = v;
          pr0[r] += v*va; pr1[r] += v*vb;
        } else {
          pr0[r] += v*va; pr1[r] += v*vb;
        }
      }
    }
    if (EPI >= 1){
      #pragma unroll
      for (int r=0;r<4;r++){
        float s0 = pr0[r], s1 = pr1[r];
        s0 += __shfl_xor(s0,8); s1 += __shfl_xor(s1,8);
        s0 += __shfl_xor(s0,4); s1 += __shfl_xor(s1,4);
        s0 += __shfl_xor(s0,2); s1 += __shfl_xor(s1,2);
        s0 += __shfl_xor(s0,1); s1 += __shfl_xor(s1,1);
        if (EPI == 1){ lmax_s = fmaxf(lmax_s, s0); lmax_d = fmaxf(lmax_d, s1); }
        if (c == 0){
          const int row = rowBase + q*4 + r;
          if (row < NNODE){
            if (EPI == 1){ os[row] = s0; od[row] = s1; }
            else { float2 y2; y2.x = s0 + vd[0]; y2.y = s1 + vd[1];
                   *(float2*)&outf[(size_t)row*2] = y2; }
          }
        }
      }
    }
  }
  if (EPI == 1){
    // wave-reduce the running max of the attention dots, 2 atomics per wave
    #pragma unroll
    for (int off=32; off>0; off>>=1){
      lmax_s = fmaxf(lmax_s, __shfl_xor(lmax_s, off));
      lmax_d = fmaxf(lmax_d, __shfl_xor(lmax_d, off));
    }
    if (lane == 0){
      atomicMax(&gm[0], fenc(lmax_s));
      atomicMax(&gm[1], fenc(lmax_d));
    }
  }
}

// ---- CSR pass 1: degree count ----
__global__ __launch_bounds__(256) void deg_k(const int* __restrict__ ei,
    int* __restrict__ cnt)
{
  int e = blockIdx.x*256 + threadIdx.x;
  if (e >= NEDGE) return;
  int dst = min(max(ei[NEDGE + e], 0), NNODE-1);
  atomicAdd(&cnt[dst], 1);
}

// ---- CSR pass 2: prefix sum (any disjoint layout works -> block-atomic bases) ----
__global__ __launch_bounds__(256) void scan_k(int* __restrict__ cntoffs,
    int* __restrict__ cursor, unsigned* __restrict__ gtot)
{
  __shared__ int wtot[4];
  __shared__ int bbase;
  const int lane = threadIdx.x & 63, wave = threadIdx.x >> 6;
  const int node = blockIdx.x*256 + threadIdx.x;
  const int mycnt = (node < NNODE) ? cntoffs[node] : 0;
  int val = mycnt;                             // inclusive wave scan
  #pragma unroll
  for (int d=1; d<64; d<<=1){
    int t = __shfl_up(val, d);
    if (lane >= d) val += t;
  }
  if (lane == 63) wtot[wave] = val;
  __syncthreads();
  if (threadIdx.x == 0){
    int run = 0;
    #pragma unroll
    for (int i=0;i<4;i++){ int t = wtot[i]; wtot[i] = run; run += t; }
    bbase = (int)atomicAdd(gtot, (unsigned)run);
  }
  __syncthreads();
  if (node < NNODE){
    const int off = bbase + wtot[wave] + val - mycnt;   // exclusive
    cntoffs[node] = off;
    cursor[node]  = off;
  }
}

// ---- CSR pass 3: scatter (src, ev) records into compact L2-resident CSR ----
__global__ __launch_bounds__(256) void scat_k(const int* __restrict__ ei,
    const float* __restrict__ a_src, const float* __restrict__ a_dst,
    int* __restrict__ cursor, int2* __restrict__ es)
{
  int e = blockIdx.x*256 + threadIdx.x;
  if (e >= NEDGE) return;
  int src = min(max(ei[e], 0), NNODE-1);
  int dst = min(max(ei[NEDGE + e], 0), NNODE-1);
  float ev = a_src[src] + a_dst[dst];
  ev = (ev >= 0.f) ? ev : 0.2f*ev;
  int pos = atomicAdd(&cursor[dst], 1);
  es[pos] = make_int2(src, __float_as_int(ev));
}

// ---- fused softmax + gather + normalize: og = softmax-agg(g) + b_gat -> bf16 hi/lo ----
// global shift M = leaky(max a_src + max a_dst) >= all e; cancels in alpha = w/z.
__global__ __launch_bounds__(256) void agg_k(const float* __restrict__ g,
    const int* __restrict__ offs, const int* __restrict__ cur,
    const int2* __restrict__ es,
    const float* __restrict__ a_src, const float* __restrict__ a_dst,
    const unsigned* __restrict__ gm, const float* __restrict__ b_gat,
    ushort* __restrict__ og_hi, ushort* __restrict__ og_lo)
{
  const int wave = threadIdx.x >> 6, lane = threadIdx.x & 63;
  const int half = lane >> 5, li = lane & 31;
  const int dst = blockIdx.x*4 + wave;
  if (dst >= NNODE) return;
  float M = fdec(gm[0]) + fdec(gm[1]);
  M = (M >= 0.f) ? M : 0.2f*M;
  const int start = offs[dst];
  const int deg = cur[dst] - start;
  const int2* __restrict__ bin = es + start;
  float ev_s = a_src[dst] + a_dst[dst];
  ev_s = (ev_s >= 0.f) ? ev_s : 0.2f*ev_s;
  f32x4 acc0 = {0,0,0,0}, acc1 = {0,0,0,0};
  float ws0 = 0.f, ws1 = 0.f;
  int j = half;
  for (; j+2 < deg; j += 4){
    const int2 p0 = bin[j], p1 = bin[j+2];
    const float w0 = __expf(__int_as_float(p0.y) - M);
    const float w1 = __expf(__int_as_float(p1.y) - M);
    const f32x4 g0 = *(const f32x4*)&g[(size_t)p0.x*DDIM + li*4];
    const f32x4 g1 = *(const f32x4*)&g[(size_t)p1.x*DDIM + li*4];
    acc0 += w0*g0; ws0 += w0;
    acc1 += w1*g1; ws1 += w1;
  }
  for (; j < deg; j += 2){
    const int2 p = bin[j];
    const float w = __expf(__int_as_float(p.y) - M);
    const f32x4 gv = *(const f32x4*)&g[(size_t)p.x*DDIM + li*4];
    acc0 += w*gv; ws0 += w;
  }
  if (half == 0){
    const float w = __expf(ev_s - M);
    const f32x4 gv = *(const f32x4*)&g[(size_t)dst*DDIM + li*4];
    acc0 += w*gv; ws0 += w;
  }
  f32x4 acc = acc0 + acc1;
  float ws = ws0 + ws1;
  acc[0] += __shfl_xor(acc[0], 32);
  acc[1] += __shfl_xor(acc[1], 32);
  acc[2] += __shfl_xor(acc[2], 32);
  acc[3] += __shfl_xor(acc[3], 32);
  ws += __shfl_xor(ws, 32);
  if (half == 0){
    const float inv = 1.f/ws;                  // ws >= w_self > 0
    ushort4 hi4, lo4; float o;
    o = acc[0]*inv + b_gat[li*4+0]; hi4.x = f2bf(o); lo4.x = f2bf(o - bf2f(hi4.x));
    o = acc[1]*inv + b_gat[li*4+1]; hi4.y = f2bf(o); lo4.y = f2bf(o - bf2f(hi4.y));
    o = acc[2]*inv + b_gat[li*4+2]; hi4.z = f2bf(o); lo4.z = f2bf(o - bf2f(hi4.z));
    o = acc[3]*inv + b_gat[li*4+3]; hi4.w = f2bf(o); lo4.w = f2bf(o - bf2f(hi4.w));
    *(ushort4*)&og_hi[(size_t)dst*DDIM + li*4] = hi4;
    *(ushort4*)&og_lo[(size_t)dst*DDIM + li*4] = lo4;
  }
}

extern "C" void kernel_launch(void* const* d_in, const int* in_sizes, int n_in,
                              void* d_out, int out_size, void* d_ws, size_t ws_size,
                              hipStream_t stream)
{
  const float* x       = (const float*)d_in[0];
  const int*   ei      = (const int*)d_in[1];
  // d_in[2] = edge_type (unused by reference)
  const float* W_in    = (const float*)d_in[3];
  const float* b_in    = (const float*)d_in[4];
  const float* W_gat   = (const float*)d_in[5];
  const float* att_src = (const float*)d_in[6];
  const float* att_dst = (const float*)d_in[7];
  const float* b_gat   = (const float*)d_in[8];
  const float* W_h     = (const float*)d_in[9];
  const float* b_h     = (const float*)d_in[10];
  const float* W_out   = (const float*)d_in[11];
  const float* b_out   = (const float*)d_in[12];

  // workspace (~77.9 MB, phase-aliased):
  //  phase1 (splitx,gemmA): xh[0,25.6M) xl[25.6M,51.2M) h_hi[51.2M,64M) h_lo[64M,76.8M)
  //  phase2 (gemmB):        g[0,25.6M) over xh (dead)
  //  phase3 (deg/scan/scat): es[25.6M,30.4M) compact CSR over xl (dead)
  //  phase4 (agg,gemmC):    og_hi[51.2M,64M) og_lo[64M,76.8M) over h (dead)
  //  [76.8M,77.9M): split weights + small arrays
  char* ws = (char*)d_ws;
  ushort*   xh      = (ushort*)  (ws + 0);
  float*    g       = (float*)   (ws + 0);
  ushort*   xl      = (ushort*)  (ws + 25600000);
  int2*     es      = (int2*)    (ws + 25600000);
  ushort*   h_hi    = (ushort*)  (ws + 51200000);
  ushort*   og_hi   = (ushort*)  (ws + 51200000);
  ushort*   h_lo    = (ushort*)  (ws + 64000000);
  ushort*   og_lo   = (ushort*)  (ws + 64000000);
  ushort*   BhA     = (ushort*)  (ws + 76800000);  // 64 KB
  ushort*   BlA     = (ushort*)  (ws + 76870000);
  ushort*   BhB     = (ushort*)  (ws + 76940000);  // 32 KB
  ushort*   BlB     = (ushort*)  (ws + 76980000);
  ushort*   BhC     = (ushort*)  (ws + 77020000);
  ushort*   BlC     = (ushort*)  (ws + 77060000);
  int*      cntoffs = (int*)     (ws + 77100000);
  int*      cursor  = (int*)     (ws + 77300000);
  float*    a_src   = (float*)   (ws + 77500000);
  float*    a_dst   = (float*)   (ws + 77700000);
  unsigned* gsmall  = (unsigned*)(ws + 77900000);  // [gmax_s, gmax_d, gtotal]

  hipMemsetAsync(cntoffs, 0, 200000, stream);
  hipMemsetAsync(gsmall,  0, 12,     stream);

  splitw_k<<<256, 256, 0, stream>>>(W_in, W_gat, W_h, BhA, BlA, BhB, BlB, BhC, BlC);
  splitx_k<<<6250, 256, 0, stream>>>(x, xh, xl);
  // gemmA: h = leaky(x @ W_in + b_in) -> bf16 hi/lo   (K=256: NT=4, 2 col-halves/block)
  gemm3_k<8,4,0><<<256, 256, 0, stream>>>(xh, xl, BhA, BlA, b_in,
      nullptr, h_hi, h_lo, nullptr, nullptr, nullptr, nullptr, nullptr);
  // gemmB: g = h @ W_gat (fp32) + a_src/a_dst + their global maxes
  gemm3_k<4,8,1><<<256, 256, 0, stream>>>(h_hi, h_lo, BhB, BlB, nullptr,
      g, nullptr, nullptr, att_src, att_dst, a_src, a_dst, gsmall);
  deg_k<<<(NEDGE+255)/256, 256, 0, stream>>>(ei, cntoffs);
  scan_k<<<(NNODE+255)/256, 256, 0, stream>>>(cntoffs, cursor, gsmall+2);
  scat_k<<<(NEDGE+255)/256, 256, 0, stream>>>(ei, a_src, a_dst, cursor, es);
  agg_k<<<12500, 256, 0, stream>>>(g, cntoffs, cursor, es, a_src, a_dst, gsmall, b_gat, og_hi, og_lo);
  // gemmC: y = leaky(og @ W_h + b_h) @ W_out + b_out  (direct store to d_out)
  gemm3_k<4,8,2><<<256, 256, 0, stream>>>(og_hi, og_lo, BhC, BlC, b_h,
      (float*)d_out, nullptr, nullptr, W_out, b_out, nullptr, nullptr, nullptr);
}

// Round 8
// 304.859 us; speedup vs baseline: 1.1044x; 1.1044x over previous
//
#include <hip/hip_runtime.h>

#define NNODE 50000
#define NEDGE 600000
#define KDIN  239
#define DDIM  128
#define NTILES 3125           // 3125*16 == 50000 exactly

typedef _Float16 half8 __attribute__((ext_vector_type(8)));
typedef _Float16 half4 __attribute__((ext_vector_type(4)));
typedef __attribute__((ext_vector_type(4))) float f32x4;

__device__ __forceinline__ ushort f2h(float f){
  union { _Float16 h; ushort u; } c; c.h = (_Float16)f; return c.u;
}
__device__ __forceinline__ float h2f(ushort u){
  union { ushort u; _Float16 h; } c; c.u = u; return (float)c.h;
}
// monotone float<->uint encoding for atomicMax on signed floats
__device__ __forceinline__ unsigned fenc(float f){
  union { float f; unsigned u; } v; v.f = f;
  return (v.u & 0x80000000u) ? ~v.u : (v.u | 0x80000000u);
}
__device__ __forceinline__ float fdec(unsigned k){
  union { unsigned u; float f; } v;
  v.u = (k & 0x80000000u) ? (k & 0x7FFFFFFFu) : ~k;
  return v.f;
}

// ---- fused prologue: x->f16[N,256], weight transposes->f16, zero cnt/gsmall ----
__global__ __launch_bounds__(256) void pre_k(const float* __restrict__ x,
    const float* __restrict__ W_in, const float* __restrict__ W_gat, const float* __restrict__ W_h,
    ushort* __restrict__ xf, ushort* __restrict__ BfA, ushort* __restrict__ BfB,
    ushort* __restrict__ BfC, int* __restrict__ cnt, unsigned* __restrict__ gsmall)
{
  const int b = blockIdx.x, t = threadIdx.x;
  if (b < 6250){                                   // x [N,239] fp32 -> [N,256] f16
    int idx = b*256 + t;                           // N*32 threads, 8 elems each
    int r = idx >> 5, c0 = (idx & 31) << 3;
    union { uint4 v; ushort u[8]; } o;
    #pragma unroll
    for (int i=0;i<8;i++){ int c = c0+i; o.u[i] = (c < KDIN) ? f2h(x[(size_t)r*KDIN + c]) : (ushort)0; }
    *(uint4*)(xf + (size_t)r*256 + c0) = o.v;
  } else if (b < 6378){                            // W_in [239,128] -> BfA[n=128][k=256]
    int idx = (b-6250)*256 + t; int n = idx >> 8, k = idx & 255;
    BfA[idx] = (k < KDIN) ? f2h(W_in[(size_t)k*DDIM + n]) : (ushort)0;
  } else if (b < 6442){                            // W_gat -> BfB[n][128]
    int idx = (b-6378)*256 + t; int n = idx >> 7, k = idx & 127;
    BfB[idx] = f2h(W_gat[(size_t)k*DDIM + n]);
  } else if (b < 6506){                            // W_h -> BfC[n][128]
    int idx = (b-6442)*256 + t; int n = idx >> 7, k = idx & 127;
    BfC[idx] = f2h(W_h[(size_t)k*DDIM + n]);
  } else if (b < 6702){                            // zero degree counters
    int i = (b-6506)*256 + t; if (i < NNODE) cnt[i] = 0;
  } else {
    if (t < 3) gsmall[t] = 0;                      // [gmax_s, gmax_d, gtotal]
  }
}

// ---- MFMA GEMM (f16 single-pass), B resident in VGPRs, grid-stride rows ----
// NBG gemm blocks; XW=1: extra blocks do degree count; XW=2: extra blocks do scan.
// EPI 0: leaky(.01)(v+bias) -> f16;  EPI 1: v -> f16 g + row dots os/od + global max
// EPI 2: h2=leaky(.01)(v+bias); y = h2@W_out + b_out -> outf
template<int KSTEPS, int NT, int EPI, int XW>
__global__ __launch_bounds__(256, 2) void gemm4_k(
    const ushort* __restrict__ Af, const ushort* __restrict__ Btf,
    const float* __restrict__ bias,
    float* __restrict__ outf, ushort* __restrict__ outh,
    const float* __restrict__ vs, const float* __restrict__ vd,
    float* __restrict__ os, float* __restrict__ od, unsigned* __restrict__ gm,
    const int* __restrict__ ei, int* __restrict__ cnt, int* __restrict__ cursor)
{
  constexpr int NBG = 512;
  constexpr int Kpad = KSTEPS*32;
  constexpr int CS  = 128/(NT*16);                 // col-splits per block
  constexpr int NRS = 4/CS;                        // row slots per block
  __shared__ int wtot[4];
  __shared__ int bbase;
  if (XW == 1 && blockIdx.x >= NBG){               // degree count
    int e = (blockIdx.x - NBG)*256 + threadIdx.x;
    if (e < NEDGE){
      int dst = min(max(ei[NEDGE + e], 0), NNODE-1);
      atomicAdd(&cnt[dst], 1);
    }
    return;
  }
  if (XW == 2 && blockIdx.x >= NBG){               // prefix-scan of degrees
    const int lane = threadIdx.x & 63, wave = threadIdx.x >> 6;
    const int node = (blockIdx.x - NBG)*256 + threadIdx.x;
    const int mycnt = (node < NNODE) ? cnt[node] : 0;
    int val = mycnt;
    #pragma unroll
    for (int d=1; d<64; d<<=1){ int tv = __shfl_up(val, d); if (lane >= d) val += tv; }
    if (lane == 63) wtot[wave] = val;
    __syncthreads();
    if (threadIdx.x == 0){
      int run = 0;
      #pragma unroll
      for (int i=0;i<4;i++){ int tv = wtot[i]; wtot[i] = run; run += tv; }
      bbase = (int)atomicAdd((unsigned*)gm + 2, (unsigned)run);
    }
    __syncthreads();
    if (node < NNODE){
      const int off = bbase + wtot[wave] + val - mycnt;
      cnt[node] = off; cursor[node] = off;
    }
    return;
  }
  const int lane = threadIdx.x & 63;
  const int wave = threadIdx.x >> 6;
  const int q = lane >> 4, c = lane & 15;
  const int colBase = (wave & (CS-1)) * (NT*16);
  const int rowSlot = wave >> (CS-1);
  // B preload: wave's col-slice x full K in registers
  half8 bf[KSTEPS][NT];
  #pragma unroll
  for (int t=0;t<NT;t++){
    const size_t bo = (size_t)(colBase + 16*t + c)*Kpad + q*8;
    #pragma unroll
    for (int s=0;s<KSTEPS;s++) bf[s][t] = *(const half8*)(Btf + bo + s*32);
  }
  float lmax_s = -3.0e38f, lmax_d = -3.0e38f;
  const int tileStride = NBG * NRS;
  for (int rt = blockIdx.x*NRS + rowSlot; rt < NTILES; rt += tileStride){
    const int rowBase = rt*16;
    const int arow = rowBase + c;                  // NTILES*16==NNODE: always in range
    half8 af[KSTEPS];
    const ushort* __restrict__ ap = Af + (size_t)arow*Kpad + q*8;
    #pragma unroll
    for (int s=0;s<KSTEPS;s++) af[s] = *(const half8*)(ap + s*32);
    f32x4 acc[NT];
    #pragma unroll
    for (int t=0;t<NT;t++) acc[t] = (f32x4){0.f,0.f,0.f,0.f};
    #pragma unroll
    for (int s=0;s<KSTEPS;s++){
      #pragma unroll
      for (int t=0;t<NT;t++)
        acc[t] = __builtin_amdgcn_mfma_f32_16x16x32_f16(af[s], bf[s][t], acc[t], 0,0,0);
    }
    // epilogue: C/D layout col=lane&15, row=(lane>>4)*4+reg  [m89/m91-verified]
    float pr0[4] = {0,0,0,0}, pr1[4] = {0,0,0,0};
    #pragma unroll
    for (int t=0;t<NT;t++){
      const int col = colBase + 16*t + c;
      const float bv = (EPI != 1) ? bias[col] : 0.f;
      float va=0.f, vb=0.f;
      if (EPI == 1){ va = vs[col]; vb = vd[col]; }
      if (EPI == 2){ va = vs[2*col]; vb = vs[2*col+1]; }
      #pragma unroll
      for (int r=0;r<4;r++){
        const int row = rowBase + q*4 + r;
        float v = acc[t][r] + bv;
        if (EPI != 1) v = (v >= 0.f) ? v : 0.01f*v;
        if (EPI == 0){
          outh[(size_t)row*DDIM + col] = f2h(v);
        } else if (EPI == 1){
          outh[(size_t)row*DDIM + col] = f2h(v);
          pr0[r] += v*va; pr1[r] += v*vb;
        } else {
          pr0[r] += v*va; pr1[r] += v*vb;
        }
      }
    }
    if (EPI >= 1){
      #pragma unroll
      for (int r=0;r<4;r++){
        float s0 = pr0[r], s1 = pr1[r];
        s0 += __shfl_xor(s0,8); s1 += __shfl_xor(s1,8);
        s0 += __shfl_xor(s0,4); s1 += __shfl_xor(s1,4);
        s0 += __shfl_xor(s0,2); s1 += __shfl_xor(s1,2);
        s0 += __shfl_xor(s0,1); s1 += __shfl_xor(s1,1);
        if (EPI == 1){ lmax_s = fmaxf(lmax_s, s0); lmax_d = fmaxf(lmax_d, s1); }
        if (c == 0){
          const int row = rowBase + q*4 + r;
          if (EPI == 1){ os[row] = s0; od[row] = s1; }
          else { float2 y2; y2.x = s0 + vd[0]; y2.y = s1 + vd[1];
                 *(float2*)&outf[(size_t)row*2] = y2; }
        }
      }
    }
  }
  if (EPI == 1){
    #pragma unroll
    for (int off=32; off>0; off>>=1){
      lmax_s = fmaxf(lmax_s, __shfl_xor(lmax_s, off));
      lmax_d = fmaxf(lmax_d, __shfl_xor(lmax_d, off));
    }
    if (lane == 0){ atomicMax(&gm[0], fenc(lmax_s)); atomicMax(&gm[1], fenc(lmax_d)); }
  }
}

// ---- CSR scatter: src index only (ev recomputed in agg) ----
__global__ __launch_bounds__(256) void scat_k(const int* __restrict__ ei,
    int* __restrict__ cursor, int* __restrict__ es)
{
  int e = blockIdx.x*256 + threadIdx.x;
  if (e >= NEDGE) return;
  int src = min(max(ei[e], 0), NNODE-1);
  int dst = min(max(ei[NEDGE + e], 0), NNODE-1);
  int pos = atomicAdd(&cursor[dst], 1);
  es[pos] = src;
}

// ---- fused softmax+gather: og[dst] = softmax-agg(g f16) + b_gat -> f16 ----
// half-wave (32 lanes) per dst; global shift M = leaky(max a_src + max a_dst)
__global__ __launch_bounds__(256) void agg_k(const ushort* __restrict__ gf,
    const int* __restrict__ offs, const int* __restrict__ cur,
    const int* __restrict__ es,
    const float* __restrict__ a_src, const float* __restrict__ a_dst,
    const unsigned* __restrict__ gm, const float* __restrict__ b_gat,
    ushort* __restrict__ og)
{
  const int lane = threadIdx.x & 63;
  const int half = lane >> 5, li = lane & 31;
  const int dst = blockIdx.x*8 + (threadIdx.x >> 6)*2 + half;
  if (dst >= NNODE) return;
  float M = fdec(gm[0]) + fdec(gm[1]);
  M = (M >= 0.f) ? M : 0.2f*M;
  const int start = offs[dst];
  const int deg = cur[dst] - start;
  const int* __restrict__ bin = es + start;
  const float ad = a_dst[dst];
  f32x4 acc0 = {0,0,0,0}, acc1 = {0,0,0,0};
  float ws0 = 0.f, ws1 = 0.f;
  int j = 0;
  for (; j+1 < deg; j += 2){                       // 2 gather streams in flight
    const int s0i = bin[j], s1i = bin[j+1];
    float e0 = a_src[s0i] + ad; e0 = (e0 >= 0.f) ? e0 : 0.2f*e0;
    float e1 = a_src[s1i] + ad; e1 = (e1 >= 0.f) ? e1 : 0.2f*e1;
    const float w0 = __expf(e0 - M), w1 = __expf(e1 - M);
    const half4 g0 = *(const half4*)(gf + (size_t)s0i*DDIM + li*4);
    const half4 g1 = *(const half4*)(gf + (size_t)s1i*DDIM + li*4);
    #pragma unroll
    for (int i=0;i<4;i++){ acc0[i] += w0*(float)g0[i]; acc1[i] += w1*(float)g1[i]; }
    ws0 += w0; ws1 += w1;
  }
  if (j < deg){
    const int si = bin[j];
    float e0 = a_src[si] + ad; e0 = (e0 >= 0.f) ? e0 : 0.2f*e0;
    const float w = __expf(e0 - M);
    const half4 gv = *(const half4*)(gf + (size_t)si*DDIM + li*4);
    #pragma unroll
    for (int i=0;i<4;i++) acc0[i] += w*(float)gv[i];
    ws0 += w;
  }
  {                                                // self-loop
    float evs = a_src[dst] + ad; evs = (evs >= 0.f) ? evs : 0.2f*evs;
    const float w = __expf(evs - M);
    const half4 gv = *(const half4*)(gf + (size_t)dst*DDIM + li*4);
    #pragma unroll
    for (int i=0;i<4;i++) acc0[i] += w*(float)gv[i];
    ws0 += w;
  }
  const float inv = 1.f/(ws0 + ws1);               // >= w_self > 0
  const float4 bg = *(const float4*)&b_gat[li*4];
  ushort4 o;
  o.x = f2h((acc0[0]+acc1[0])*inv + bg.x);
  o.y = f2h((acc0[1]+acc1[1])*inv + bg.y);
  o.z = f2h((acc0[2]+acc1[2])*inv + bg.z);
  o.w = f2h((acc0[3]+acc1[3])*inv + bg.w);
  *(ushort4*)(og + (size_t)dst*DDIM + li*4) = o;
}

extern "C" void kernel_launch(void* const* d_in, const int* in_sizes, int n_in,
                              void* d_out, int out_size, void* d_ws, size_t ws_size,
                              hipStream_t stream)
{
  const float* x       = (const float*)d_in[0];
  const int*   ei      = (const int*)d_in[1];
  // d_in[2] = edge_type (unused by reference)
  const float* W_in    = (const float*)d_in[3];
  const float* b_in    = (const float*)d_in[4];
  const float* W_gat   = (const float*)d_in[5];
  const float* att_src = (const float*)d_in[6];
  const float* att_dst = (const float*)d_in[7];
  const float* b_gat   = (const float*)d_in[8];
  const float* W_h     = (const float*)d_in[9];
  const float* b_h     = (const float*)d_in[10];
  const float* W_out   = (const float*)d_in[11];
  const float* b_out   = (const float*)d_in[12];

  // workspace (~55 MB):
  //  [0     ,25.6M): xf16 [N,256]; og f16 [N,128] aliases [0,12.8M) after gemmA,
  //                  es CSR int [12.8M,15.2M) after gemmA
  //  [25.6M ,38.4M): h f16    [38.4M,51.2M): g f16
  //  [51.2M ,...  ): BfA/BfB/BfC, cnt, cursor, a_src, a_dst, gsmall
  char* ws = (char*)d_ws;
  ushort*   xf     = (ushort*)  (ws + 0);
  ushort*   og     = (ushort*)  (ws + 0);
  int*      es     = (int*)     (ws + 12800000);
  ushort*   hf     = (ushort*)  (ws + 25600000);
  ushort*   gf     = (ushort*)  (ws + 38400000);
  ushort*   BfA    = (ushort*)  (ws + 51200000);  // 64 KB
  ushort*   BfB    = (ushort*)  (ws + 51300000);  // 32 KB
  ushort*   BfC    = (ushort*)  (ws + 51400000);  // 32 KB
  int*      cnt    = (int*)     (ws + 51500000);
  int*      cursor = (int*)     (ws + 51700000);
  float*    a_src  = (float*)   (ws + 51900000);
  float*    a_dst  = (float*)   (ws + 52100000);
  unsigned* gsmall = (unsigned*)(ws + 52300000);  // [gmax_s, gmax_d, gtotal]

  pre_k<<<6703, 256, 0, stream>>>(x, W_in, W_gat, W_h, xf, BfA, BfB, BfC, cnt, gsmall);
  // gemmA (h = leaky(x@W_in+b_in) -> f16) || degree count
  gemm4_k<8,4,0,1><<<512+2344, 256, 0, stream>>>(xf, BfA, b_in,
      nullptr, hf, nullptr, nullptr, nullptr, nullptr, nullptr, ei, cnt, nullptr);
  // gemmB (g = h@W_gat -> f16, + a_src/a_dst + global maxes) || prefix scan
  gemm4_k<4,8,1,2><<<512+196, 256, 0, stream>>>(hf, BfB, nullptr,
      nullptr, gf, att_src, att_dst, a_src, a_dst, gsmall, nullptr, cnt, cursor);
  scat_k<<<2344, 256, 0, stream>>>(ei, cursor, es);
  agg_k<<<6250, 256, 0, stream>>>(gf, cnt, cursor, es, a_src, a_dst, gsmall, b_gat, og);
  // gemmC: y = leaky(og@W_h+b_h) @ W_out + b_out -> d_out fp32
  gemm4_k<4,8,2,0><<<512, 256, 0, stream>>>(og, BfC, b_h,
      (float*)d_out, nullptr, W_out, b_out, nullptr, nullptr, nullptr, nullptr, nullptr, nullptr);
}